// Round 1
// 64.550 us; speedup vs baseline: 1.0082x; 1.0082x over previous
//
#include <hip/hip_runtime.h>
#include <math.h>

#define TWO_PI_F 6.2831853071795864769f
#define LOG_2PI_F 1.8378770664093454836f
#define EPS_F 1e-6f
#define PI_F 3.14159265358979323846f

// Compute the Kent orthonormal frame (g1,g2,g3) from angles.
// Angles are bounded (|x| <= pi) so hardware __sincosf is safe.
__device__ __forceinline__ void kent_frame(float eta, float alpha, float psi,
                                           float& g1x, float& g1y, float& g1z,
                                           float& g2x, float& g2y, float& g2z,
                                           float& g3x, float& g3y, float& g3z) {
    float ca, sa, ce, se, cp, sp;
    __sincosf(alpha, &sa, &ca);
    __sincosf(eta,   &se, &ce);
    __sincosf(psi,   &sp, &cp);
    g1x = ca;        g1y = sa * ce;                  g1z = sa * se;
    g2x = -cp * sa;  g2y = cp * ca * ce - sp * se;   g2z = cp * ca * se + sp * ce;
    g3x = sp * sa;   g3y = -sp * ca * ce - cp * se;  g3z = -sp * ca * se + cp * ce;
}

// One thread per row (pred rows then target rows).
// fw: [N][10]  = {Ex0,Ex1,Ex2, S00,S11,S22, 2S01,2S02,2S12, A}
// gw: [10][M]  = {kb*gb1(3), bb*Ddiag(3), bb*Doff(3), c_b}  (transposed for coalescing)
//
// Algebraic simplification of the reference's exp(log-chain):
//   l1  = exp(c_k  - c) = (k^2 - k - 4b^2) / (km*kp)           * e^-EPS
//   ekk = exp(c_kk - c) = P2 / (km*kp)^2                        * e^-EPS
//   eb  = exp(c_b  - c) = 4*k*b*e^-k / (km*kp)                  * e^-EPS
// (the EPS the reference adds to the log-denominators becomes a
//  multiplicative e^-EPS ~ (1-EPS); km*kp >> EPS for this input range so
//  the EPS inside log(km*kp+EPS) is absorbed.)
__global__ __launch_bounds__(256) void kent_precompute(
    const float* __restrict__ pred, const float* __restrict__ targ,
    float* __restrict__ fw, float* __restrict__ gw, int N, int M)
{
    const float eme = 1.0f - EPS_F;   // e^-EPS to first order
    int i = blockIdx.x * blockDim.x + threadIdx.x;
    if (i < N) {
        const float* r = pred + (size_t)i * 5;
        float eta = r[0], alpha = r[1], psi = r[2], kap = r[3], bet = r[4];
        float g1x,g1y,g1z,g2x,g2y,g2z,g3x,g3y,g3z;
        kent_frame(eta, alpha, psi, g1x,g1y,g1z, g2x,g2y,g2z, g3x,g3y,g3z);

        float km = kap - 2.f*bet, kp = kap + 2.f*bet;
        float prod = km * kp;
        float inv  = 1.f / prod;
        float c    = LOG_2PI_F + kap - 0.5f * __logf(prod + EPS_F);

        float b2 = bet*bet;
        float k2 = kap*kap;
        float P1 = k2 - kap - 4.f*b2;
        float P2 = k2*k2 - 2.f*kap*k2 + (2.f - 8.f*b2)*k2 + 8.f*b2*kap
                 + 16.f*b2*b2 + 4.f*b2;

        float l1  = P1 * inv * eme;
        float ekk = P2 * inv * inv * eme;
        float eb  = 4.f * kap * bet * __expf(-kap) * inv * eme;
        float l2 = 0.5f*(1.f - ekk + eb);
        float l3 = 0.5f*(1.f - ekk - eb);

        float Ex = l1*g1x, Ey = l1*g1y, Ez = l1*g1z;
        float S00 = l1*g1x*g1x + l2*g2x*g2x + l3*g3x*g3x;
        float S11 = l1*g1y*g1y + l2*g2y*g2y + l3*g3y*g3y;
        float S22 = l1*g1z*g1z + l2*g2z*g2z + l3*g3z*g3z;
        float S01 = l1*g1x*g1y + l2*g2x*g2y + l3*g3x*g3y;
        float S02 = l1*g1x*g1z + l2*g2x*g2z + l3*g3x*g3z;
        float S12 = l1*g1y*g1z + l2*g2y*g2z + l3*g3y*g3z;

        // qa2 = g2^T S g2 ; qa3 = g3^T S g3 (numerically, matching reference)
        float qa2 = S00*g2x*g2x + S11*g2y*g2y + S22*g2z*g2z
                  + 2.f*(S01*g2x*g2y + S02*g2x*g2z + S12*g2y*g2z);
        float qa3 = S00*g3x*g3x + S11*g3y*g3y + S22*g3z*g3z
                  + 2.f*(S01*g3x*g3y + S02*g3x*g3z + S12*g3y*g3z);
        float dg1Ex = g1x*Ex + g1y*Ey + g1z*Ez;
        float A = -c + kap*dg1Ex + bet*(qa2 - qa3);

        float* f = fw + (size_t)i * 10;
        f[0]=Ex; f[1]=Ey; f[2]=Ez;
        f[3]=S00; f[4]=S11; f[5]=S22;
        f[6]=2.f*S01; f[7]=2.f*S02; f[8]=2.f*S12;
        f[9]=A;
    } else if (i < N + M) {
        int m = i - N;
        const float* r = targ + (size_t)m * 5;
        float eta = r[0], alpha = r[1], psi = r[2], kap = r[3], bet = r[4];
        float g1x,g1y,g1z,g2x,g2y,g2z,g3x,g3y,g3z;
        kent_frame(eta, alpha, psi, g1x,g1y,g1z, g2x,g2y,g2z, g3x,g3y,g3z);

        float km = kap - 2.f*bet, kp = kap + 2.f*bet;
        float cB = LOG_2PI_F + kap - 0.5f * __logf(km*kp + EPS_F);

        float D00 = g2x*g2x - g3x*g3x;
        float D11 = g2y*g2y - g3y*g3y;
        float D22 = g2z*g2z - g3z*g3z;
        float D01 = g2x*g2y - g3x*g3y;
        float D02 = g2x*g2z - g3x*g3z;
        float D12 = g2y*g2z - g3y*g3z;

        gw[0*(size_t)M + m] = kap*g1x;
        gw[1*(size_t)M + m] = kap*g1y;
        gw[2*(size_t)M + m] = kap*g1z;
        gw[3*(size_t)M + m] = bet*D00;
        gw[4*(size_t)M + m] = bet*D11;
        gw[5*(size_t)M + m] = bet*D22;
        gw[6*(size_t)M + m] = bet*D01;
        gw[7*(size_t)M + m] = bet*D02;
        gw[8*(size_t)M + m] = bet*D12;
        gw[9*(size_t)M + m] = cB;
    }
}

// out[n,m] = A[n] + B[m] - sum_k f[n,k]*g[m,k]
// Each block: 8 n-rows x 1024 m-cols. Each thread: 4 m via float4, 8 n.
__global__ __launch_bounds__(256) void kent_kld_main(
    const float* __restrict__ fw, const float* __restrict__ gw,
    float* __restrict__ out, int N, int M)
{
    int t = threadIdx.x;
    int m0 = blockIdx.x * 1024 + t * 4;
    int n0 = blockIdx.y * 8;
    if (m0 >= M) return;

    if (m0 + 3 < M) {
        float4 G[10];
#pragma unroll
        for (int k = 0; k < 10; ++k)
            G[k] = *(const float4*)(&gw[(size_t)k * M + m0]);
#pragma unroll
        for (int rr = 0; rr < 8; ++rr) {
            int n = n0 + rr;
            if (n >= N) break;
            const float* f = fw + (size_t)n * 10;
            float A = f[9];
            float4 o;
            o.x = A + G[9].x; o.y = A + G[9].y;
            o.z = A + G[9].z; o.w = A + G[9].w;
#pragma unroll
            for (int k = 0; k < 9; ++k) {
                float fk = f[k];
                o.x = fmaf(-fk, G[k].x, o.x);
                o.y = fmaf(-fk, G[k].y, o.y);
                o.z = fmaf(-fk, G[k].z, o.z);
                o.w = fmaf(-fk, G[k].w, o.w);
            }
            *(float4*)(&out[(size_t)n * M + m0]) = o;
        }
    } else {
        // scalar tail (unused for M=2048 but keeps generality)
        for (int mm = m0; mm < M; ++mm) {
            for (int rr = 0; rr < 8; ++rr) {
                int n = n0 + rr;
                if (n >= N) break;
                const float* f = fw + (size_t)n * 10;
                float acc = f[9] + gw[9*(size_t)M + mm];
                for (int k = 0; k < 9; ++k)
                    acc = fmaf(-f[k], gw[(size_t)k * M + mm], acc);
                out[(size_t)n * M + mm] = acc;
            }
        }
    }
}

extern "C" void kernel_launch(void* const* d_in, const int* in_sizes, int n_in,
                              void* d_out, int out_size, void* d_ws, size_t ws_size,
                              hipStream_t stream) {
    const float* pred = (const float*)d_in[0];
    const float* targ = (const float*)d_in[1];
    int N = in_sizes[0] / 5;
    int M = in_sizes[1] / 5;

    float* fw = (float*)d_ws;               // N*10 floats
    float* gw = fw + (size_t)N * 10;        // 10*M floats
    float* out = (float*)d_out;

    int total = N + M;
    kent_precompute<<<(total + 255) / 256, 256, 0, stream>>>(pred, targ, fw, gw, N, M);

    dim3 grid((M + 1023) / 1024, (N + 7) / 8);
    kent_kld_main<<<grid, 256, 0, stream>>>(fw, gw, out, N, M);
}